// Round 2
// baseline (4833.895 us; speedup 1.0000x reference)
//
#include <hip/hip_runtime.h>
#include <stdint.h>

typedef __attribute__((ext_vector_type(8))) short short8;
typedef __attribute__((ext_vector_type(4))) float f32x4;
typedef __attribute__((ext_vector_type(4))) unsigned short ushort4v;

__device__ inline unsigned short f2bf(float x) {
  union { float f; unsigned u; } v; v.f = x;
  unsigned r = (v.u + 0x7FFFu + ((v.u >> 16) & 1u)) >> 16;
  return (unsigned short)r;
}
__device__ inline float bf2f(unsigned short b) {
  union { unsigned u; float f; } v; v.u = ((unsigned)b) << 16;
  return v.f;
}

__device__ inline void gload_lds16(const void* g, void* l) {
  __builtin_amdgcn_global_load_lds(
      (const __attribute__((address_space(1))) unsigned int*)g,
      (__attribute__((address_space(3))) unsigned int*)l, 16, 0, 0);
}

// ---------- elementwise helpers ----------
__global__ void k_convert(const float* __restrict__ src, unsigned short* __restrict__ dst, int n4) {
  int i = blockIdx.x * blockDim.x + threadIdx.x;
  if (i < n4) {
    f32x4 v = *(const f32x4*)(src + (size_t)i * 4);
    ushort4v r;
    r.x = f2bf(v.x); r.y = f2bf(v.y); r.z = f2bf(v.z); r.w = f2bf(v.w);
    *(ushort4v*)(dst + (size_t)i * 4) = r;
  }
}

__global__ void k_bias(const float* __restrict__ a, const float* __restrict__ b,
                       float* __restrict__ o, int n) {
  int i = blockIdx.x * blockDim.x + threadIdx.x;
  if (i < n) o[i] = a[i] + b[i];
}

__global__ void k_init(unsigned short* __restrict__ h0, float* __restrict__ c) {
  int i = blockIdx.x * blockDim.x + threadIdx.x; // 65536 threads
  h0[i] = 0;
  c[i] = 0.f;
}

// ---------- bf16 GEMM: C = A @ B^T (+bias), A [M,K], B [N,K], all bf16, f32 accum ----------
// MODE 0: C bf16, natural row order.
// MODE 1: C bf16, row remap (b*512+t) -> (t*64+b)  (for gx in [T,B,4H] layout)
template <int MODE>
__global__ __launch_bounds__(256) void k_gemm_bt(
    const unsigned short* __restrict__ A,
    const unsigned short* __restrict__ Bm,
    const float* __restrict__ bias,
    unsigned short* __restrict__ C,
    int M, int N, int K) {
  __shared__ unsigned short As[128 * 32];
  __shared__ unsigned short Bs[128 * 32];
  const int tid = threadIdx.x;
  const int m0 = blockIdx.y * 128, n0 = blockIdx.x * 128;
  const int lane = tid & 63, w = tid >> 6;
  const int wm = (w >> 1) * 64, wn = (w & 1) * 64;

  f32x4 acc[4][4] = {};

  const int ar0 = tid >> 2;          // 0..63
  const int ak = (tid & 3) * 8;      // 0,8,16,24
  const unsigned short* Ag0 = A + (size_t)(m0 + ar0) * K + ak;
  const unsigned short* Ag1 = A + (size_t)(m0 + 64 + ar0) * K + ak;
  const unsigned short* Bg0 = Bm + (size_t)(n0 + ar0) * K + ak;
  const unsigned short* Bg1 = Bm + (size_t)(n0 + 64 + ar0) * K + ak;
  unsigned short* Al = As + tid * 8;   // wave-uniform base + lane*16B within each wave
  unsigned short* Bl = Bs + tid * 8;

  const int lr = lane & 15, lk = (lane >> 4) * 8;

  for (int k0 = 0; k0 < K; k0 += 32) {
    gload_lds16(Ag0 + k0, Al);
    gload_lds16(Ag1 + k0, Al + 2048);   // rows 64..127 of As (FIXED: was +4096, overflowed into Bs)
    gload_lds16(Bg0 + k0, Bl);
    gload_lds16(Bg1 + k0, Bl + 2048);
    __syncthreads();
    short8 a[4], b[4];
#pragma unroll
    for (int i = 0; i < 4; i++) a[i] = *(const short8*)&As[(wm + i * 16 + lr) * 32 + lk];
#pragma unroll
    for (int j = 0; j < 4; j++) b[j] = *(const short8*)&Bs[(wn + j * 16 + lr) * 32 + lk];
#pragma unroll
    for (int i = 0; i < 4; i++)
#pragma unroll
      for (int j = 0; j < 4; j++)
        acc[i][j] = __builtin_amdgcn_mfma_f32_16x16x32_bf16(a[i], b[j], acc[i][j], 0, 0, 0);
    __syncthreads();
  }

  const int lq = (lane >> 4) * 4;
#pragma unroll
  for (int j = 0; j < 4; j++) {
    int col = n0 + wn + j * 16 + lr;
    float bv = bias[col];
#pragma unroll
    for (int i = 0; i < 4; i++) {
      int rowb = m0 + wm + i * 16 + lq;
#pragma unroll
      for (int r = 0; r < 4; r++) {
        int row = rowb + r;
        float v = acc[i][j][r] + bv;
        size_t orow = (MODE == 1) ? ((size_t)(row & 511) * 64 + (size_t)(row >> 9)) : (size_t)row;
        C[orow * (size_t)N + col] = f2bf(v);
      }
    }
  }
}

// ---------- LSTM step: gates = gx[t] + h_in @ W_hh^T, cell update ----------
// grid 256 blocks; block gt owns h-cols [gt*4, gt*4+4) i.e. gate rows {s*1024 + gt*4 + q}
// h is double-buffered across t (h_in read-only here, h_out written) -> no inter-block race.
__global__ __launch_bounds__(256) void k_step(
    const unsigned short* __restrict__ gx,    // [T*B, 4096] bf16, row = t*64+b
    const unsigned short* __restrict__ Whh,   // [4096, 1024] bf16
    const unsigned short* __restrict__ h_in,  // [64,1024] bf16
    unsigned short* __restrict__ h_out,       // [64,1024] bf16
    float* __restrict__ c,                    // [64,1024] f32
    float* __restrict__ out,                  // [B,T,H] f32
    int t) {
  __shared__ unsigned short Ws[16 * 1024];  // 32 KiB
  __shared__ float Gs[64 * 16];             // 4 KiB
  const int tid = threadIdx.x, gt = blockIdx.x;

  // stage W_hh slice: 16 rows x 1024, rows = (lc>>2)*1024 + gt*4 + (lc&3)
#pragma unroll
  for (int i = 0; i < 8; i++) {
    int c0 = tid + 256 * i;                 // 16B chunk id, 0..2047
    int lc = c0 >> 7;                       // 0..15
    int k = (c0 & 127) * 8;                 // 0..1016
    int grow = (lc >> 2) * 1024 + gt * 4 + (lc & 3);
    gload_lds16(Whh + (size_t)grow * 1024 + k, (void*)(Ws + c0 * 8));
  }
  __syncthreads();

  const int w = tid >> 6, lane = tid & 63;
  const int lr = lane & 15, lk8 = (lane >> 4) * 8;
  const unsigned short* hrow = h_in + (size_t)(w * 16 + lr) * 1024 + lk8;
  const unsigned short* wsrow = Ws + lr * 1024 + lk8;

  f32x4 acc0 = {}, acc1 = {};
#pragma unroll 4
  for (int kk = 0; kk < 32; kk += 2) {
    short8 a0 = *(const short8*)(hrow + kk * 32);
    short8 b0 = *(const short8*)(wsrow + kk * 32);
    short8 a1 = *(const short8*)(hrow + kk * 32 + 32);
    short8 b1 = *(const short8*)(wsrow + kk * 32 + 32);
    acc0 = __builtin_amdgcn_mfma_f32_16x16x32_bf16(a0, b0, acc0, 0, 0, 0);
    acc1 = __builtin_amdgcn_mfma_f32_16x16x32_bf16(a1, b1, acc1, 0, 0, 0);
  }
  f32x4 accs = acc0 + acc1;

  // add gx contribution; scatter to Gs[batch][lc]
  const int gcol = (lr >> 2) * 1024 + gt * 4 + (lr & 3);
#pragma unroll
  for (int r = 0; r < 4; r++) {
    int b_loc = w * 16 + (lane >> 4) * 4 + r;
    float gv = bf2f(gx[(size_t)(t * 64 + b_loc) * 4096 + gcol]) + accs[r];
    Gs[b_loc * 16 + lr] = gv;
  }
  __syncthreads();

  // cell update: one thread per (batch, q), q in [0,4)
  const int b_loc = tid >> 2, q = tid & 3;
  float gi = Gs[b_loc * 16 + 0 + q];
  float gf = Gs[b_loc * 16 + 4 + q];
  float gg = Gs[b_loc * 16 + 8 + q];
  float go = Gs[b_loc * 16 + 12 + q];
  float i_ = 1.f / (1.f + __expf(-gi));
  float f_ = 1.f / (1.f + __expf(-gf));
  float g_ = tanhf(gg);
  float o_ = 1.f / (1.f + __expf(-go));
  const int col = gt * 4 + q;
  float cold = c[(size_t)b_loc * 1024 + col];
  float cn = f_ * cold + i_ * g_;
  float hn = o_ * tanhf(cn);
  c[(size_t)b_loc * 1024 + col] = cn;
  h_out[(size_t)b_loc * 1024 + col] = f2bf(hn);
  out[((size_t)b_loc * 512 + t) * 1024 + col] = hn;
}

__global__ void k_final(const float* __restrict__ out, const float* __restrict__ c,
                        float* __restrict__ hout, float* __restrict__ cout) {
  int i = blockIdx.x * blockDim.x + threadIdx.x;  // 65536
  int b = i >> 10, col = i & 1023;
  hout[i] = out[((size_t)b * 512 + 511) * 1024 + col];
  cout[i] = c[i];
}

extern "C" void kernel_launch(void* const* d_in, const int* in_sizes, int n_in,
                              void* d_out, int out_size, void* d_ws, size_t ws_size,
                              hipStream_t stream) {
  const float* x = (const float*)d_in[0];
  const float* W_emb = (const float*)d_in[1];
  const float* b_emb = (const float*)d_in[2];
  const float* W_ih = (const float*)d_in[3];
  const float* W_hh = (const float*)d_in[4];
  const float* b_ih = (const float*)d_in[5];
  const float* b_hh = (const float*)d_in[6];

  char* ws = (char*)d_ws;
  unsigned short* x_bf    = (unsigned short*)(ws + 0);           // 16,777,216 B
  unsigned short* Wemb_bf = (unsigned short*)(ws + 16777216);    // 262,144 B
  unsigned short* Wih_bf  = (unsigned short*)(ws + 17039360);    // 4,194,304 B
  unsigned short* Whh_bf  = (unsigned short*)(ws + 21233664);    // 8,388,608 B
  float* bias_sum         = (float*)(ws + 29622272);             // 16,384 B
  unsigned short* xe      = (unsigned short*)(ws + 29638656);    // 33,554,432 B
  unsigned short* gx      = (unsigned short*)(ws + 63193088);    // 268,435,456 B
  unsigned short* hbuf0   = (unsigned short*)(ws + 331628544);   // 131,072 B
  unsigned short* hbuf1   = (unsigned short*)(ws + 331759616);   // 131,072 B
  float* cbuf             = (float*)(ws + 331890688);            // 262,144 B

  float* out = (float*)d_out;
  float* hout = out + (size_t)64 * 512 * 1024;
  float* cout = hout + 65536;

  k_convert<<<8192, 256, 0, stream>>>(x, x_bf, 2097152);
  k_convert<<<128, 256, 0, stream>>>(W_emb, Wemb_bf, 32768);
  k_convert<<<2048, 256, 0, stream>>>(W_ih, Wih_bf, 524288);
  k_convert<<<4096, 256, 0, stream>>>(W_hh, Whh_bf, 1048576);
  k_bias<<<16, 256, 0, stream>>>(b_ih, b_hh, bias_sum, 4096);
  k_init<<<256, 256, 0, stream>>>(hbuf0, cbuf);

  // xe = x @ W_emb^T + b_emb : M=32768, N=512, K=256
  k_gemm_bt<0><<<dim3(4, 256), 256, 0, stream>>>(x_bf, Wemb_bf, b_emb, xe, 32768, 512, 256);
  // gx = xe @ W_ih^T + (b_ih+b_hh) : M=32768, N=4096, K=512, rows remapped to [T,B]
  k_gemm_bt<1><<<dim3(32, 256), 256, 0, stream>>>(xe, Wih_bf, bias_sum, gx, 32768, 4096, 512);

  unsigned short* hb[2] = {hbuf0, hbuf1};
  for (int t = 0; t < 512; ++t)
    k_step<<<256, 256, 0, stream>>>(gx, Whh_bf, hb[t & 1], hb[(t + 1) & 1], cbuf, out, t);

  k_final<<<256, 256, 0, stream>>>(out, cbuf, hout, cout);
}